// Round 1
// baseline (4023.470 us; speedup 1.0000x reference)
//
#include <hip/hip_runtime.h>
#include <math.h>

#define TT 4096
#define DD 1024
#define NH 16
#define HD 64

// ---------------- fp32 tiled GEMM ----------------
// C[M,N] = A[M,K] * B[K,N], row-major. 64x64 tile, 256 threads, 4x4 per thread.
// MODE 0: plain write to C0.
// MODE 1: qkv scatter: n<1024 -> Q, <2048 -> K, else V, layout [h][t][hd].
template <int MODE>
__global__ __launch_bounds__(256) void gemm_f32(
    const float* __restrict__ A, const float* __restrict__ B,
    float* __restrict__ C0, float* __restrict__ C1, float* __restrict__ C2,
    int M, int N, int K)
{
    __shared__ float As[16][65];
    __shared__ float Bs[16][65];
    const int tid = threadIdx.x;
    const int tx = tid & 15;   // col group (n)
    const int ty = tid >> 4;   // row group (m)
    const int n0 = blockIdx.x * 64;
    const int m0 = blockIdx.y * 64;

    float acc[4][4];
#pragma unroll
    for (int i = 0; i < 4; i++)
#pragma unroll
        for (int j = 0; j < 4; j++) acc[i][j] = 0.f;

    const int a_c = tid & 15, a_r = tid >> 4;   // A tile: 64 rows x 16 k
    const int b_c = tid & 63, b_r = tid >> 6;   // B tile: 16 k x 64 cols

    for (int k0 = 0; k0 < K; k0 += 16) {
#pragma unroll
        for (int i = 0; i < 4; i++)
            As[a_c][a_r + 16 * i] = A[(size_t)(m0 + a_r + 16 * i) * K + k0 + a_c];
#pragma unroll
        for (int i = 0; i < 4; i++)
            Bs[b_r + 4 * i][b_c] = B[(size_t)(k0 + b_r + 4 * i) * N + n0 + b_c];
        __syncthreads();
#pragma unroll
        for (int kk = 0; kk < 16; kk++) {
            float a[4], b[4];
#pragma unroll
            for (int i = 0; i < 4; i++) a[i] = As[kk][ty * 4 + i];
#pragma unroll
            for (int j = 0; j < 4; j++) b[j] = Bs[kk][tx * 4 + j];
#pragma unroll
            for (int i = 0; i < 4; i++)
#pragma unroll
                for (int j = 0; j < 4; j++) acc[i][j] += a[i] * b[j];
        }
        __syncthreads();
    }

#pragma unroll
    for (int i = 0; i < 4; i++) {
        const int m = m0 + ty * 4 + i;
#pragma unroll
        for (int j = 0; j < 4; j++) {
            const int n = n0 + tx * 4 + j;
            if (MODE == 0) {
                C0[(size_t)m * N + n] = acc[i][j];
            } else {
                const int which = n >> 10;       // 0:q 1:k 2:v
                const int col = n & 1023;
                const int h = col >> 6, d = col & 63;
                float* dst = which == 0 ? C0 : (which == 1 ? C1 : C2);
                dst[((size_t)h * TT + m) * HD + d] = acc[i][j];
            }
        }
    }
}

// ---------------- RoPE in-place on Q and K ----------------
__global__ __launch_bounds__(256) void rope_kernel(float* __restrict__ Q,
                                                   float* __restrict__ Kb)
{
    const int idx = blockIdx.x * 256 + threadIdx.x;  // over NH*TT*32
    const int i = idx & 31;
    const int t = (idx >> 5) & (TT - 1);
    const int h = idx >> 17;
    if (h >= NH) return;

    const float inv = expf(-(float)i * (logf(10000.0f) / 32.0f));
    const float f = (float)t * inv;
    const float c = cosf(f), s = sinf(f);
    const size_t base = ((size_t)h * TT + t) * HD + i;

    float q1 = Q[base], q2 = Q[base + 32];
    Q[base]      = q1 * c - q2 * s;
    Q[base + 32] = q2 * c + q1 * s;
    float k1 = Kb[base], k2 = Kb[base + 32];
    Kb[base]      = k1 * c - k2 * s;
    Kb[base + 32] = k2 * c + k1 * s;
}

// ---------------- causal attention, one block per (h, q-row) ----------------
__global__ __launch_bounds__(256) void attn_kernel(
    const float* __restrict__ Q, const float* __restrict__ Kb,
    const float* __restrict__ V, float* __restrict__ Y)
{
    __shared__ float s_sc[TT];                 // 16 KB scores
    __shared__ __align__(16) float s_q[HD];
    __shared__ float s_part[4][HD];
    __shared__ float s_red[8];
    __shared__ float s_m, s_sum;

    const int q_idx = blockIdx.x;
    const int h = blockIdx.y;
    const int tid = threadIdx.x;
    const int L = q_idx + 1;
    const float* Kh = Kb + (size_t)h * TT * HD;
    const float* Vh = V + (size_t)h * TT * HD;

    if (tid < HD) s_q[tid] = Q[((size_t)h * TT + q_idx) * HD + tid];
    __syncthreads();

    // phase 1: scores s_j = q . k_j * 0.125
    const int quad = tid & 3;        // 16-dim chunk
    const int keyofs = tid >> 2;     // 0..63
    const float4* qp = (const float4*)&s_q[quad * 16];
    const float4 q0 = qp[0], q1 = qp[1], q2 = qp[2], q3 = qp[3];

    for (int j0 = 0; j0 < L; j0 += 64) {
        const int j = j0 + keyofs;
        float partial = 0.f;
        if (j < L) {
            const float4* kp = (const float4*)(Kh + (size_t)j * HD + quad * 16);
            float4 k0 = kp[0], k1 = kp[1], k2 = kp[2], k3 = kp[3];
            partial = q0.x * k0.x + q0.y * k0.y + q0.z * k0.z + q0.w * k0.w
                    + q1.x * k1.x + q1.y * k1.y + q1.z * k1.z + q1.w * k1.w
                    + q2.x * k2.x + q2.y * k2.y + q2.z * k2.z + q2.w * k2.w
                    + q3.x * k3.x + q3.y * k3.y + q3.z * k3.z + q3.w * k3.w;
        }
        partial += __shfl_xor(partial, 1);
        partial += __shfl_xor(partial, 2);
        if (quad == 0 && j < L) s_sc[j] = partial * 0.125f;
    }
    __syncthreads();

    // phase 2: max
    float lmax = -1e30f;
    for (int j = tid; j < L; j += 256) lmax = fmaxf(lmax, s_sc[j]);
#pragma unroll
    for (int o = 32; o; o >>= 1) lmax = fmaxf(lmax, __shfl_xor(lmax, o));
    if ((tid & 63) == 0) s_red[tid >> 6] = lmax;
    __syncthreads();
    if (tid == 0)
        s_m = fmaxf(fmaxf(s_red[0], s_red[1]), fmaxf(s_red[2], s_red[3]));
    __syncthreads();
    const float m = s_m;

    // phase 3: exp + sum
    float lsum = 0.f;
    for (int j = tid; j < L; j += 256) {
        float p = __expf(s_sc[j] - m);
        s_sc[j] = p;
        lsum += p;
    }
#pragma unroll
    for (int o = 32; o; o >>= 1) lsum += __shfl_xor(lsum, o);
    if ((tid & 63) == 0) s_red[4 + (tid >> 6)] = lsum;
    __syncthreads();
    if (tid == 0) s_sum = s_red[4] + s_red[5] + s_red[6] + s_red[7];
    __syncthreads();
    const float inv_sum = 1.0f / s_sum;

    // phase 4: y[d] = sum_j p_j * V[j][d] / sum
    const int d = tid & 63;
    const int g = tid >> 6;
    float acc = 0.f;
    for (int j = g; j < L; j += 4) acc += s_sc[j] * Vh[(size_t)j * HD + d];
    s_part[g][d] = acc;
    __syncthreads();
    if (g == 0) {
        float y = (s_part[0][d] + s_part[1][d] + s_part[2][d] + s_part[3][d]) * inv_sum;
        Y[(size_t)q_idx * DD + h * HD + d] = y;   // [t][h*64+d] layout for proj
    }
}

extern "C" void kernel_launch(void* const* d_in, const int* in_sizes, int n_in,
                              void* d_out, int out_size, void* d_ws, size_t ws_size,
                              hipStream_t stream)
{
    const float* x      = (const float*)d_in[0];
    const float* w_qkv  = (const float*)d_in[1];
    const float* w_proj = (const float*)d_in[2];
    float* out = (float*)d_out;

    const size_t per = (size_t)NH * TT * HD;   // 4.19M floats
    float* Q  = (float*)d_ws;
    float* Kw = Q + per;
    float* Vw = Kw + per;
    float* Yw = Vw + per;

    dim3 blk(256);

    // 1) qkv = x @ w_qkv, scattered into Q/K/V [h][t][hd]
    gemm_f32<1><<<dim3(3072 / 64, TT / 64), blk, 0, stream>>>(
        x, w_qkv, Q, Kw, Vw, TT, 3 * DD, DD);

    // 2) RoPE on Q, K
    rope_kernel<<<(NH * TT * 32) / 256, blk, 0, stream>>>(Q, Kw);

    // 3) causal attention -> Y [t][D]
    attn_kernel<<<dim3(TT, NH), blk, 0, stream>>>(Q, Kw, Vw, Yw);

    // 4) out = Y @ w_proj
    gemm_f32<0><<<dim3(DD / 64, TT / 64), blk, 0, stream>>>(
        Yw, w_proj, out, nullptr, nullptr, TT, DD, DD);
}

// Round 2
// 1089.604 us; speedup vs baseline: 3.6926x; 3.6926x over previous
//
#include <hip/hip_runtime.h>
#include <math.h>

#define TT 4096
#define DD 1024
#define NH 16
#define HD 64

typedef __attribute__((ext_vector_type(8))) _Float16 half8v;
typedef __attribute__((ext_vector_type(4))) _Float16 half4v;
typedef __attribute__((ext_vector_type(4))) float f32x4;

// ---------------- fp32 tiled GEMM ----------------
// C[M,N] = A[M,K] * B[K,N], row-major. 64x64 tile, 256 threads, 4x4 per thread.
// MODE 0: plain fp32 write to C0.
// MODE 1: qkv scatter: Q->C0 fp32, K->C1 fp32, V->C2 fp16, layout [h][t][hd].
template <int MODE>
__global__ __launch_bounds__(256) void gemm_f32(
    const float* __restrict__ A, const float* __restrict__ B,
    float* __restrict__ C0, float* __restrict__ C1, _Float16* __restrict__ C2,
    int M, int N, int K)
{
    __shared__ float As[16][65];
    __shared__ float Bs[16][65];
    const int tid = threadIdx.x;
    const int tx = tid & 15;
    const int ty = tid >> 4;
    const int n0 = blockIdx.x * 64;
    const int m0 = blockIdx.y * 64;

    float acc[4][4];
#pragma unroll
    for (int i = 0; i < 4; i++)
#pragma unroll
        for (int j = 0; j < 4; j++) acc[i][j] = 0.f;

    const int a_c = tid & 15, a_r = tid >> 4;
    const int b_c = tid & 63, b_r = tid >> 6;

    for (int k0 = 0; k0 < K; k0 += 16) {
#pragma unroll
        for (int i = 0; i < 4; i++)
            As[a_c][a_r + 16 * i] = A[(size_t)(m0 + a_r + 16 * i) * K + k0 + a_c];
#pragma unroll
        for (int i = 0; i < 4; i++)
            Bs[b_r + 4 * i][b_c] = B[(size_t)(k0 + b_r + 4 * i) * N + n0 + b_c];
        __syncthreads();
#pragma unroll
        for (int kk = 0; kk < 16; kk++) {
            float a[4], b[4];
#pragma unroll
            for (int i = 0; i < 4; i++) a[i] = As[kk][ty * 4 + i];
#pragma unroll
            for (int j = 0; j < 4; j++) b[j] = Bs[kk][tx * 4 + j];
#pragma unroll
            for (int i = 0; i < 4; i++)
#pragma unroll
                for (int j = 0; j < 4; j++) acc[i][j] += a[i] * b[j];
        }
        __syncthreads();
    }

#pragma unroll
    for (int i = 0; i < 4; i++) {
        const int m = m0 + ty * 4 + i;
#pragma unroll
        for (int j = 0; j < 4; j++) {
            const int n = n0 + tx * 4 + j;
            if (MODE == 0) {
                C0[(size_t)m * N + n] = acc[i][j];
            } else {
                const int which = n >> 10;       // 0:q 1:k 2:v
                const int col = n & 1023;
                const int h = col >> 6, d = col & 63;
                const size_t off = ((size_t)h * TT + m) * HD + d;
                if (which == 0) C0[off] = acc[i][j];
                else if (which == 1) C1[off] = acc[i][j];
                else C2[off] = (_Float16)acc[i][j];
            }
        }
    }
}

// ---------------- RoPE + cast to fp16 (Q scaled by 1/sqrt(HD)) ----------------
__global__ __launch_bounds__(256) void rope_cast(
    const float* __restrict__ Qf, const float* __restrict__ Kf,
    _Float16* __restrict__ Qh, _Float16* __restrict__ Kh)
{
    const int idx = blockIdx.x * 256 + threadIdx.x;  // over NH*TT*32
    const int i = idx & 31;
    const int t = (idx >> 5) & (TT - 1);
    const int h = idx >> 17;
    if (h >= NH) return;

    const float inv = expf(-(float)i * (logf(10000.0f) / 32.0f));
    const float f = (float)t * inv;
    const float c = cosf(f), s = sinf(f);
    const size_t base = ((size_t)h * TT + t) * HD + i;

    float q1 = Qf[base], q2 = Qf[base + 32];
    Qh[base]      = (_Float16)((q1 * c - q2 * s) * 0.125f);
    Qh[base + 32] = (_Float16)((q2 * c + q1 * s) * 0.125f);
    float k1 = Kf[base], k2 = Kf[base + 32];
    Kh[base]      = (_Float16)(k1 * c - k2 * s);
    Kh[base + 32] = (_Float16)(k2 * c + k1 * s);
}

// ---------------- MFMA flash attention ----------------
// Block: 256 threads = 4 waves; wave w handles q rows [q0+16w, q0+16w+16).
// Iterate 32-key tiles; K tile + V^T tile in LDS; online softmax.
__global__ __launch_bounds__(256) void attn_kernel(
    const _Float16* __restrict__ Qh, const _Float16* __restrict__ Kh,
    const _Float16* __restrict__ Vh, float* __restrict__ Y)
{
    __shared__ __align__(16) _Float16 Ks[32][72];   // [key][d], pad->2-way max
    __shared__ __align__(16) _Float16 Vt[64][44];   // [d][key], pad->conflict-free reads
    __shared__ __align__(16) float    Ps[4][16][36];// per-wave P, [m][k], pad

    const int tid  = threadIdx.x;
    const int wave = tid >> 6;
    const int lane = tid & 63;
    const int quad = lane >> 4;
    const int n16  = lane & 15;
    const int h  = blockIdx.y;
    const int q0 = blockIdx.x * 64;

    const _Float16* Qg = Qh + (size_t)h * TT * HD;
    const _Float16* Kg = Kh + (size_t)h * TT * HD;
    const _Float16* Vg = Vh + (size_t)h * TT * HD;

    // Q fragments (A-layout: m = lane&15, k = quad*8+j), two 32-d chunks
    const int qrowA = q0 + wave * 16 + n16;
    half8v aQ0 = *(const half8v*)(Qg + (size_t)qrowA * HD + 0 + quad * 8);
    half8v aQ1 = *(const half8v*)(Qg + (size_t)qrowA * HD + 32 + quad * 8);

    f32x4 O[4];
#pragma unroll
    for (int d = 0; d < 4; d++) O[d] = (f32x4){0.f, 0.f, 0.f, 0.f};
    float m_r[4] = {-1e30f, -1e30f, -1e30f, -1e30f};
    float l_r[4] = {0.f, 0.f, 0.f, 0.f};

    const int nTiles = (q0 >> 5) + 2;

    for (int it = 0; it < nTiles; ++it) {
        const int j0 = it * 32;
        __syncthreads();   // previous iter's LDS readers done

        // stage K tile: [32 keys][64 d]
        {
            const int j = tid >> 3, c = tid & 7;
            *(half8v*)&Ks[j][c * 8] =
                *(const half8v*)(Kg + (size_t)(j0 + j) * HD + c * 8);
        }
        // stage V tile transposed: Vt[d][j]
        {
            const int j = tid & 31, c = tid >> 5;   // c: 0..7
            half8v v = *(const half8v*)(Vg + (size_t)(j0 + j) * HD + c * 8);
#pragma unroll
            for (int e = 0; e < 8; e++) Vt[c * 8 + e][j] = v[e];
        }
        __syncthreads();

        // S = Q * K^T  (two 16-key subtiles, two 32-d chunks)
        f32x4 S[2];
#pragma unroll
        for (int s = 0; s < 2; s++) {
            S[s] = (f32x4){0.f, 0.f, 0.f, 0.f};
            half8v bK0 = *(const half8v*)&Ks[s * 16 + n16][0 + quad * 8];
            S[s] = __builtin_amdgcn_mfma_f32_16x16x32_f16(aQ0, bK0, S[s], 0, 0, 0);
            half8v bK1 = *(const half8v*)&Ks[s * 16 + n16][32 + quad * 8];
            S[s] = __builtin_amdgcn_mfma_f32_16x16x32_f16(aQ1, bK1, S[s], 0, 0, 0);
        }

        // online softmax; C-layout: row = quad*4+r, col = n16
#pragma unroll
        for (int r = 0; r < 4; r++) {
            const int qg = q0 + wave * 16 + quad * 4 + r;
            float x0 = (j0 + n16      <= qg) ? S[0][r] : -1e30f;
            float x1 = (j0 + 16 + n16 <= qg) ? S[1][r] : -1e30f;
            float t = fmaxf(x0, x1);
            t = fmaxf(t, __shfl_xor(t, 1));
            t = fmaxf(t, __shfl_xor(t, 2));
            t = fmaxf(t, __shfl_xor(t, 4));
            t = fmaxf(t, __shfl_xor(t, 8));
            const float mn = fmaxf(m_r[r], t);
            const float al = __expf(m_r[r] - mn);
            const float p0 = __expf(x0 - mn);
            const float p1 = __expf(x1 - mn);
            float rs = p0 + p1;
            rs += __shfl_xor(rs, 1);
            rs += __shfl_xor(rs, 2);
            rs += __shfl_xor(rs, 4);
            rs += __shfl_xor(rs, 8);
            l_r[r] = l_r[r] * al + rs;
            m_r[r] = mn;
#pragma unroll
            for (int d = 0; d < 4; d++) O[d][r] *= al;
            Ps[wave][quad * 4 + r][n16]      = p0;
            Ps[wave][quad * 4 + r][16 + n16] = p1;
        }

        // P: C-layout -> A-layout via LDS (same wave; compiler orders lgkmcnt)
        float4 pA = *(const float4*)&Ps[wave][n16][quad * 8];
        float4 pB = *(const float4*)&Ps[wave][n16][quad * 8 + 4];
        half8v aP = {(_Float16)pA.x, (_Float16)pA.y, (_Float16)pA.z, (_Float16)pA.w,
                     (_Float16)pB.x, (_Float16)pB.y, (_Float16)pB.z, (_Float16)pB.w};

        // O += P * V   (B-frag: n = d-sub, k = key j)
#pragma unroll
        for (int d = 0; d < 4; d++) {
            half4v lo = *(const half4v*)&Vt[d * 16 + n16][quad * 8];
            half4v hi = *(const half4v*)&Vt[d * 16 + n16][quad * 8 + 4];
            half8v bV = {lo[0], lo[1], lo[2], lo[3], hi[0], hi[1], hi[2], hi[3]};
            O[d] = __builtin_amdgcn_mfma_f32_16x16x32_f16(aP, bV, O[d], 0, 0, 0);
        }
    }

    // epilogue: Y[t][h*64+d] = O / l
#pragma unroll
    for (int r = 0; r < 4; r++) {
        const float inv = 1.0f / l_r[r];
        const int qg = q0 + wave * 16 + quad * 4 + r;
        float* yrow = Y + (size_t)qg * DD + h * HD;
#pragma unroll
        for (int d = 0; d < 4; d++)
            yrow[d * 16 + n16] = O[d][r] * inv;
    }
}

extern "C" void kernel_launch(void* const* d_in, const int* in_sizes, int n_in,
                              void* d_out, int out_size, void* d_ws, size_t ws_size,
                              hipStream_t stream)
{
    const float* x      = (const float*)d_in[0];
    const float* w_qkv  = (const float*)d_in[1];
    const float* w_proj = (const float*)d_in[2];
    float* out = (float*)d_out;

    const size_t per = (size_t)NH * TT * HD;        // 4.19M elements
    char* ws = (char*)d_ws;
    float*     Qf = (float*)ws;                     // also reused as Y after rope
    float*     Yw = (float*)ws;
    float*     Kf = (float*)(ws + per * 4);
    _Float16*  Qh = (_Float16*)(ws + per * 8);
    _Float16*  Kh = (_Float16*)(ws + per * 8 + per * 2);
    _Float16*  Vh = (_Float16*)(ws + per * 8 + per * 4);

    dim3 blk(256);

    // 1) qkv = x @ w_qkv -> Qf, Kf (fp32), Vh (fp16), layout [h][t][hd]
    gemm_f32<1><<<dim3(3072 / 64, TT / 64), blk, 0, stream>>>(
        x, w_qkv, Qf, Kf, Vh, TT, 3 * DD, DD);

    // 2) RoPE + cast (Q scaled by 0.125)
    rope_cast<<<(NH * TT * 32) / 256, blk, 0, stream>>>(Qf, Kf, Qh, Kh);

    // 3) flash attention -> Yw [t][D] fp32 (overlays dead Qf)
    attn_kernel<<<dim3(TT / 64, NH), blk, 0, stream>>>(Qh, Kh, Vh, Yw);

    // 4) out = Yw @ w_proj
    gemm_f32<0><<<dim3(DD / 64, TT / 64), blk, 0, stream>>>(
        Yw, w_proj, out, nullptr, nullptr, TT, DD, DD);
}

// Round 3
// 519.516 us; speedup vs baseline: 7.7447x; 2.0973x over previous
//
#include <hip/hip_runtime.h>
#include <math.h>

#define TT 4096
#define DD 1024
#define NH 16
#define HD 64

typedef __attribute__((ext_vector_type(8))) _Float16 half8v;
typedef __attribute__((ext_vector_type(4))) _Float16 half4v;
typedef __attribute__((ext_vector_type(4))) float f32x4;

#define GLDS16(g, l)                                                        \
    __builtin_amdgcn_global_load_lds(                                       \
        (const __attribute__((address_space(1))) void*)(g),                 \
        (__attribute__((address_space(3))) void*)(l), 16, 0, 0)

// ---------------- cast x -> fp16 ----------------
__global__ __launch_bounds__(256) void cast_x(const float* __restrict__ X,
                                              _Float16* __restrict__ Xh)
{
    const int i = (blockIdx.x * 256 + threadIdx.x) * 8;
    float4 a = *(const float4*)&X[i];
    float4 b = *(const float4*)&X[i + 4];
    half8v o = {(_Float16)a.x, (_Float16)a.y, (_Float16)a.z, (_Float16)a.w,
                (_Float16)b.x, (_Float16)b.y, (_Float16)b.z, (_Float16)b.w};
    *(half8v*)&Xh[i] = o;
}

// ---------------- transpose+cast W[K][N] fp32 -> WT[N][K] fp16 ----------------
__global__ __launch_bounds__(256) void transpose_cast(
    const float* __restrict__ W, _Float16* __restrict__ WT, int K, int N)
{
    __shared__ float tile[64][65];
    const int t = threadIdx.x;
    const int k0 = blockIdx.y * 64, n0 = blockIdx.x * 64;
    const int c = (t & 15) * 4, r = t >> 4;
#pragma unroll
    for (int i = 0; i < 4; i++) {
        float4 v = *(const float4*)&W[(size_t)(k0 + r + 16 * i) * N + n0 + c];
        tile[r + 16 * i][c + 0] = v.x;
        tile[r + 16 * i][c + 1] = v.y;
        tile[r + 16 * i][c + 2] = v.z;
        tile[r + 16 * i][c + 3] = v.w;
    }
    __syncthreads();
#pragma unroll
    for (int i = 0; i < 4; i++) {
        const int n = r + 16 * i;
        half4v o;
        o[0] = (_Float16)tile[c + 0][n];
        o[1] = (_Float16)tile[c + 1][n];
        o[2] = (_Float16)tile[c + 2][n];
        o[3] = (_Float16)tile[c + 3][n];
        *(half4v*)&WT[(size_t)(n0 + n) * K + k0 + c] = o;
    }
}

// ---------------- fp16 MFMA GEMM: C[M,N] = A[M,K] * Bt[N,K]^T ----------------
// 128x128 tile, 256 threads = 4 waves, each wave 64x64 (4x4 MFMA 16x16x32).
// MODE 0: write fp32 C0[M][N].
// MODE 1: qkv scatter fp16: n<1024->Q, <2048->K, else V, layout [h][t][hd].
template <int MODE>
__global__ __launch_bounds__(256) void gemm_h(
    const _Float16* __restrict__ A, const _Float16* __restrict__ Bt,
    float* __restrict__ C0, _Float16* __restrict__ Q,
    _Float16* __restrict__ Kk, _Float16* __restrict__ V,
    int M, int N, int K)
{
    __shared__ _Float16 As[128 * 32];
    __shared__ _Float16 Bs[128 * 32];
    const int tid  = threadIdx.x;
    const int wave = tid >> 6;
    const int lane = tid & 63;
    const int quad = lane >> 4;
    const int n16  = lane & 15;
    const int n0 = blockIdx.x * 128;
    const int m0 = blockIdx.y * 128;
    const int wr = (wave & 1) * 64;
    const int wc = (wave >> 1) * 64;

    f32x4 acc[4][4];
#pragma unroll
    for (int i = 0; i < 4; i++)
#pragma unroll
        for (int j = 0; j < 4; j++) acc[i][j] = (f32x4){0.f, 0.f, 0.f, 0.f};

    const int srow = tid >> 2;            // 0..63
    const int scol = (tid & 3) * 8;       // halves
    const _Float16* Ag = A + (size_t)(m0 + srow) * K + scol;
    const _Float16* Bg = Bt + (size_t)(n0 + srow) * K + scol;
    _Float16* AsW = As + (size_t)(tid >> 6) * 512;   // wave-uniform base
    _Float16* BsW = Bs + (size_t)(tid >> 6) * 512;

    for (int k0 = 0; k0 < K; k0 += 32) {
        __syncthreads();
        GLDS16(Ag + k0, AsW);
        GLDS16(Ag + (size_t)64 * K + k0, AsW + 2048);
        GLDS16(Bg + k0, BsW);
        GLDS16(Bg + (size_t)64 * K + k0, BsW + 2048);
        __syncthreads();

        half8v aF[4], bF[4];
#pragma unroll
        for (int i = 0; i < 4; i++)
            aF[i] = *(const half8v*)&As[(size_t)(wr + i * 16 + n16) * 32 + quad * 8];
#pragma unroll
        for (int j = 0; j < 4; j++)
            bF[j] = *(const half8v*)&Bs[(size_t)(wc + j * 16 + n16) * 32 + quad * 8];
#pragma unroll
        for (int i = 0; i < 4; i++)
#pragma unroll
            for (int j = 0; j < 4; j++)
                acc[i][j] = __builtin_amdgcn_mfma_f32_16x16x32_f16(
                    aF[i], bF[j], acc[i][j], 0, 0, 0);
    }

#pragma unroll
    for (int i = 0; i < 4; i++) {
#pragma unroll
        for (int j = 0; j < 4; j++) {
#pragma unroll
            for (int r = 0; r < 4; r++) {
                const int m = m0 + wr + i * 16 + quad * 4 + r;
                const int n = n0 + wc + j * 16 + n16;
                const float val = acc[i][j][r];
                if (MODE == 0) {
                    C0[(size_t)m * N + n] = val;
                } else {
                    const int which = n >> 10;
                    const int col = n & 1023;
                    const int h = col >> 6, d = col & 63;
                    const size_t off = ((size_t)h * TT + m) * HD + d;
                    if (which == 0) Q[off] = (_Float16)val;
                    else if (which == 1) Kk[off] = (_Float16)val;
                    else V[off] = (_Float16)val;
                }
            }
        }
    }
}

// ---------------- RoPE in-place on fp16 Q,K (Q scaled by 0.125) ----------------
__global__ __launch_bounds__(256) void rope_h(_Float16* __restrict__ Q,
                                              _Float16* __restrict__ Kb)
{
    const int idx = blockIdx.x * 256 + threadIdx.x;  // over NH*TT*32
    const int i = idx & 31;
    const int t = (idx >> 5) & (TT - 1);
    const int h = idx >> 17;
    if (h >= NH) return;

    const float inv = expf(-(float)i * (logf(10000.0f) / 32.0f));
    const float f = (float)t * inv;
    const float c = cosf(f), s = sinf(f);
    const size_t base = ((size_t)h * TT + t) * HD + i;

    float q1 = (float)Q[base], q2 = (float)Q[base + 32];
    Q[base]      = (_Float16)((q1 * c - q2 * s) * 0.125f);
    Q[base + 32] = (_Float16)((q2 * c + q1 * s) * 0.125f);
    float k1 = (float)Kb[base], k2 = (float)Kb[base + 32];
    Kb[base]      = (_Float16)(k1 * c - k2 * s);
    Kb[base + 32] = (_Float16)(k2 * c + k1 * s);
}

// ---------------- MFMA flash attention ----------------
__global__ __launch_bounds__(256) void attn_kernel(
    const _Float16* __restrict__ Qh, const _Float16* __restrict__ Kh,
    const _Float16* __restrict__ Vh, _Float16* __restrict__ Y)
{
    __shared__ __align__(16) _Float16 Ks[32][72];
    __shared__ __align__(16) _Float16 Vt[64][44];
    __shared__ __align__(16) float    Ps[4][16][36];

    const int tid  = threadIdx.x;
    const int wave = tid >> 6;
    const int lane = tid & 63;
    const int quad = lane >> 4;
    const int n16  = lane & 15;
    const int h  = blockIdx.y;
    const int q0 = blockIdx.x * 64;

    const _Float16* Qg = Qh + (size_t)h * TT * HD;
    const _Float16* Kg = Kh + (size_t)h * TT * HD;
    const _Float16* Vg = Vh + (size_t)h * TT * HD;

    const int qrowA = q0 + wave * 16 + n16;
    half8v aQ0 = *(const half8v*)(Qg + (size_t)qrowA * HD + 0 + quad * 8);
    half8v aQ1 = *(const half8v*)(Qg + (size_t)qrowA * HD + 32 + quad * 8);

    f32x4 O[4];
#pragma unroll
    for (int d = 0; d < 4; d++) O[d] = (f32x4){0.f, 0.f, 0.f, 0.f};
    float m_r[4] = {-1e30f, -1e30f, -1e30f, -1e30f};
    float l_r[4] = {0.f, 0.f, 0.f, 0.f};

    const int nTiles = (q0 >> 5) + 2;

    for (int it = 0; it < nTiles; ++it) {
        const int j0 = it * 32;
        __syncthreads();

        {
            const int j = tid >> 3, c = tid & 7;
            *(half8v*)&Ks[j][c * 8] =
                *(const half8v*)(Kg + (size_t)(j0 + j) * HD + c * 8);
        }
        {
            const int j = tid & 31, c = tid >> 5;
            half8v v = *(const half8v*)(Vg + (size_t)(j0 + j) * HD + c * 8);
#pragma unroll
            for (int e = 0; e < 8; e++) Vt[c * 8 + e][j] = v[e];
        }
        __syncthreads();

        f32x4 S[2];
#pragma unroll
        for (int s = 0; s < 2; s++) {
            S[s] = (f32x4){0.f, 0.f, 0.f, 0.f};
            half8v bK0 = *(const half8v*)&Ks[s * 16 + n16][0 + quad * 8];
            S[s] = __builtin_amdgcn_mfma_f32_16x16x32_f16(aQ0, bK0, S[s], 0, 0, 0);
            half8v bK1 = *(const half8v*)&Ks[s * 16 + n16][32 + quad * 8];
            S[s] = __builtin_amdgcn_mfma_f32_16x16x32_f16(aQ1, bK1, S[s], 0, 0, 0);
        }

#pragma unroll
        for (int r = 0; r < 4; r++) {
            const int qg = q0 + wave * 16 + quad * 4 + r;
            float x0 = (j0 + n16      <= qg) ? S[0][r] : -1e30f;
            float x1 = (j0 + 16 + n16 <= qg) ? S[1][r] : -1e30f;
            float t = fmaxf(x0, x1);
            t = fmaxf(t, __shfl_xor(t, 1));
            t = fmaxf(t, __shfl_xor(t, 2));
            t = fmaxf(t, __shfl_xor(t, 4));
            t = fmaxf(t, __shfl_xor(t, 8));
            const float mn = fmaxf(m_r[r], t);
            const float al = __expf(m_r[r] - mn);
            const float p0 = __expf(x0 - mn);
            const float p1 = __expf(x1 - mn);
            float rs = p0 + p1;
            rs += __shfl_xor(rs, 1);
            rs += __shfl_xor(rs, 2);
            rs += __shfl_xor(rs, 4);
            rs += __shfl_xor(rs, 8);
            l_r[r] = l_r[r] * al + rs;
            m_r[r] = mn;
#pragma unroll
            for (int d = 0; d < 4; d++) O[d][r] *= al;
            Ps[wave][quad * 4 + r][n16]      = p0;
            Ps[wave][quad * 4 + r][16 + n16] = p1;
        }

        float4 pA = *(const float4*)&Ps[wave][n16][quad * 8];
        float4 pB = *(const float4*)&Ps[wave][n16][quad * 8 + 4];
        half8v aP = {(_Float16)pA.x, (_Float16)pA.y, (_Float16)pA.z, (_Float16)pA.w,
                     (_Float16)pB.x, (_Float16)pB.y, (_Float16)pB.z, (_Float16)pB.w};

#pragma unroll
        for (int d = 0; d < 4; d++) {
            half4v lo = *(const half4v*)&Vt[d * 16 + n16][quad * 8];
            half4v hi = *(const half4v*)&Vt[d * 16 + n16][quad * 8 + 4];
            half8v bV = {lo[0], lo[1], lo[2], lo[3], hi[0], hi[1], hi[2], hi[3]};
            O[d] = __builtin_amdgcn_mfma_f32_16x16x32_f16(aP, bV, O[d], 0, 0, 0);
        }
    }

#pragma unroll
    for (int r = 0; r < 4; r++) {
        const float inv = 1.0f / l_r[r];
        const int qg = q0 + wave * 16 + quad * 4 + r;
        _Float16* yrow = Y + (size_t)qg * DD + h * HD;
#pragma unroll
        for (int d = 0; d < 4; d++)
            yrow[d * 16 + n16] = (_Float16)(O[d][r] * inv);
    }
}

extern "C" void kernel_launch(void* const* d_in, const int* in_sizes, int n_in,
                              void* d_out, int out_size, void* d_ws, size_t ws_size,
                              hipStream_t stream)
{
    const float* x      = (const float*)d_in[0];
    const float* w_qkv  = (const float*)d_in[1];
    const float* w_proj = (const float*)d_in[2];
    float* out = (float*)d_out;

    char* ws = (char*)d_ws;
    const size_t MB = 1u << 20;
    _Float16* xh  = (_Float16*)(ws);               //  8 MB
    _Float16* WqT = (_Float16*)(ws + 8 * MB);      //  6 MB
    _Float16* WpT = (_Float16*)(ws + 14 * MB);     //  2 MB
    _Float16* Qh  = (_Float16*)(ws + 16 * MB);     //  8 MB
    _Float16* Kh  = (_Float16*)(ws + 24 * MB);     //  8 MB
    _Float16* Vh  = (_Float16*)(ws + 32 * MB);     //  8 MB
    _Float16* Yh  = (_Float16*)(ws + 40 * MB);     //  8 MB

    dim3 blk(256);

    cast_x<<<(TT * DD) / (256 * 8), blk, 0, stream>>>(x, xh);
    transpose_cast<<<dim3(3072 / 64, DD / 64), blk, 0, stream>>>(w_qkv, WqT, DD, 3 * DD);
    transpose_cast<<<dim3(DD / 64, DD / 64), blk, 0, stream>>>(w_proj, WpT, DD, DD);

    // qkv = x @ w_qkv -> Qh,Kh,Vh fp16 [h][t][hd]
    gemm_h<1><<<dim3(3072 / 128, TT / 128), blk, 0, stream>>>(
        xh, WqT, nullptr, Qh, Kh, Vh, TT, 3 * DD, DD);

    rope_h<<<(NH * TT * 32) / 256, blk, 0, stream>>>(Qh, Kh);

    attn_kernel<<<dim3(TT / 64, NH), blk, 0, stream>>>(Qh, Kh, Vh, Yh);

    // out = Y @ w_proj (fp32 out)
    gemm_h<0><<<dim3(DD / 128, TT / 128), blk, 0, stream>>>(
        Yh, WpT, out, nullptr, nullptr, nullptr, TT, DD, DD);
}

// Round 4
// 312.113 us; speedup vs baseline: 12.8911x; 1.6645x over previous
//
#include <hip/hip_runtime.h>
#include <math.h>

#define TT 4096
#define DD 1024
#define NH 16
#define HD 64

typedef __attribute__((ext_vector_type(8))) _Float16 half8v;
typedef __attribute__((ext_vector_type(4))) _Float16 half4v;
typedef __attribute__((ext_vector_type(4))) float f32x4;

#define GLDS16(g, l)                                                        \
    __builtin_amdgcn_global_load_lds(                                       \
        (const __attribute__((address_space(1))) void*)(g),                 \
        (__attribute__((address_space(3))) void*)(l), 16, 0, 0)

// ---------------- cast x -> fp16 ----------------
__global__ __launch_bounds__(256) void cast_x(const float* __restrict__ X,
                                              _Float16* __restrict__ Xh)
{
    const int i = (blockIdx.x * 256 + threadIdx.x) * 8;
    float4 a = *(const float4*)&X[i];
    float4 b = *(const float4*)&X[i + 4];
    half8v o = {(_Float16)a.x, (_Float16)a.y, (_Float16)a.z, (_Float16)a.w,
                (_Float16)b.x, (_Float16)b.y, (_Float16)b.z, (_Float16)b.w};
    *(half8v*)&Xh[i] = o;
}

// ---------------- transpose+cast W[K][N] fp32 -> WT[N][K] fp16 ----------------
__global__ __launch_bounds__(256) void transpose_cast(
    const float* __restrict__ W, _Float16* __restrict__ WT, int K, int N)
{
    __shared__ float tile[64][65];
    const int t = threadIdx.x;
    const int k0 = blockIdx.y * 64, n0 = blockIdx.x * 64;
    const int c = (t & 15) * 4, r = t >> 4;
#pragma unroll
    for (int i = 0; i < 4; i++) {
        float4 v = *(const float4*)&W[(size_t)(k0 + r + 16 * i) * N + n0 + c];
        tile[r + 16 * i][c + 0] = v.x;
        tile[r + 16 * i][c + 1] = v.y;
        tile[r + 16 * i][c + 2] = v.z;
        tile[r + 16 * i][c + 3] = v.w;
    }
    __syncthreads();
#pragma unroll
    for (int i = 0; i < 4; i++) {
        const int n = r + 16 * i;
        half4v o;
        o[0] = (_Float16)tile[c + 0][n];
        o[1] = (_Float16)tile[c + 1][n];
        o[2] = (_Float16)tile[c + 2][n];
        o[3] = (_Float16)tile[c + 3][n];
        *(half4v*)&WT[(size_t)(n0 + n) * K + k0 + c] = o;
    }
}

// ---------------- fp16 MFMA GEMM: C[M,N] = A[M,K] * Bt[N,K]^T ----------------
template <int MODE>
__global__ __launch_bounds__(256) void gemm_h(
    const _Float16* __restrict__ A, const _Float16* __restrict__ Bt,
    float* __restrict__ C0, _Float16* __restrict__ Q,
    _Float16* __restrict__ Kk, _Float16* __restrict__ V,
    int M, int N, int K)
{
    __shared__ _Float16 As[128 * 32];
    __shared__ _Float16 Bs[128 * 32];
    const int tid  = threadIdx.x;
    const int wave = tid >> 6;
    const int lane = tid & 63;
    const int quad = lane >> 4;
    const int n16  = lane & 15;
    const int n0 = blockIdx.x * 128;
    const int m0 = blockIdx.y * 128;
    const int wr = (wave & 1) * 64;
    const int wc = (wave >> 1) * 64;

    f32x4 acc[4][4];
#pragma unroll
    for (int i = 0; i < 4; i++)
#pragma unroll
        for (int j = 0; j < 4; j++) acc[i][j] = (f32x4){0.f, 0.f, 0.f, 0.f};

    const int srow = tid >> 2;
    const int scol = (tid & 3) * 8;
    const _Float16* Ag = A + (size_t)(m0 + srow) * K + scol;
    const _Float16* Bg = Bt + (size_t)(n0 + srow) * K + scol;
    _Float16* AsW = As + (size_t)wave * 512;
    _Float16* BsW = Bs + (size_t)wave * 512;

    for (int k0 = 0; k0 < K; k0 += 32) {
        __syncthreads();
        GLDS16(Ag + k0, AsW);
        GLDS16(Ag + (size_t)64 * K + k0, AsW + 2048);
        GLDS16(Bg + k0, BsW);
        GLDS16(Bg + (size_t)64 * K + k0, BsW + 2048);
        __syncthreads();

        half8v aF[4], bF[4];
#pragma unroll
        for (int i = 0; i < 4; i++)
            aF[i] = *(const half8v*)&As[(size_t)(wr + i * 16 + n16) * 32 + quad * 8];
#pragma unroll
        for (int j = 0; j < 4; j++)
            bF[j] = *(const half8v*)&Bs[(size_t)(wc + j * 16 + n16) * 32 + quad * 8];
#pragma unroll
        for (int i = 0; i < 4; i++)
#pragma unroll
            for (int j = 0; j < 4; j++)
                acc[i][j] = __builtin_amdgcn_mfma_f32_16x16x32_f16(
                    aF[i], bF[j], acc[i][j], 0, 0, 0);
    }

#pragma unroll
    for (int i = 0; i < 4; i++) {
#pragma unroll
        for (int j = 0; j < 4; j++) {
#pragma unroll
            for (int r = 0; r < 4; r++) {
                const int m = m0 + wr + i * 16 + quad * 4 + r;
                const int n = n0 + wc + j * 16 + n16;
                const float val = acc[i][j][r];
                if (MODE == 0) {
                    C0[(size_t)m * N + n] = val;
                } else {
                    const int which = n >> 10;
                    const int col = n & 1023;
                    const int h = col >> 6, d = col & 63;
                    const size_t off = ((size_t)h * TT + m) * HD + d;
                    if (which == 0) Q[off] = (_Float16)val;
                    else if (which == 1) Kk[off] = (_Float16)val;
                    else V[off] = (_Float16)val;
                }
            }
        }
    }
}

// ---------------- RoPE in-place; Q scaled by 0.125*log2(e) ----------------
__global__ __launch_bounds__(256) void rope_h(_Float16* __restrict__ Q,
                                              _Float16* __restrict__ Kb)
{
    const int idx = blockIdx.x * 256 + threadIdx.x;
    const int i = idx & 31;
    const int t = (idx >> 5) & (TT - 1);
    const int h = idx >> 17;
    if (h >= NH) return;

    const float inv = expf(-(float)i * (logf(10000.0f) / 32.0f));
    const float f = (float)t * inv;
    const float c = cosf(f), s = sinf(f);
    const size_t base = ((size_t)h * TT + t) * HD + i;
    const float QS = 0.125f * 1.44269504f;   // fold log2e for exp2 softmax

    float q1 = (float)Q[base], q2 = (float)Q[base + 32];
    Q[base]      = (_Float16)((q1 * c - q2 * s) * QS);
    Q[base + 32] = (_Float16)((q2 * c + q1 * s) * QS);
    float k1 = (float)Kb[base], k2 = (float)Kb[base + 32];
    Kb[base]      = (_Float16)(k1 * c - k2 * s);
    Kb[base + 32] = (_Float16)(k2 * c + k1 * s);
}

// ---------------- V transpose: [h][t][d] -> [h][d][t] ----------------
__global__ __launch_bounds__(256) void transpose_v(
    const _Float16* __restrict__ V, _Float16* __restrict__ Vt)
{
    __shared__ _Float16 tile[256][72];
    const int h = blockIdx.y;
    const int t0 = blockIdx.x * 256;
    const int tid = threadIdx.x;
    const _Float16* Vg = V + (size_t)h * TT * HD;
    _Float16* Vo = Vt + (size_t)h * TT * HD;

#pragma unroll
    for (int i = 0; i < 4; i++) {
        const int chunk = tid + 256 * i;             // 1024 chunks of 16 halves
        const int row = chunk >> 2, c = (chunk & 3) * 16;
        half8v v0 = *(const half8v*)(Vg + (size_t)(t0 + row) * HD + c);
        half8v v1 = *(const half8v*)(Vg + (size_t)(t0 + row) * HD + c + 8);
        *(half8v*)&tile[row][c] = v0;
        *(half8v*)&tile[row][c + 8] = v1;
    }
    __syncthreads();

    const int s = tid & 15;
#pragma unroll
    for (int dd = 0; dd < 4; ++dd) {
        const int d = dd * 16 + (tid >> 4);
        half8v o0, o1;
#pragma unroll
        for (int e = 0; e < 8; e++) o0[e] = tile[s * 16 + e][d];
#pragma unroll
        for (int e = 0; e < 8; e++) o1[e] = tile[s * 16 + 8 + e][d];
        *(half8v*)(Vo + (size_t)d * TT + t0 + s * 16) = o0;
        *(half8v*)(Vo + (size_t)d * TT + t0 + s * 16 + 8) = o1;
    }
}

// ---------------- MFMA flash attention, no-max exact softmax ----------------
// Block: 4 waves x 32 q-rows = 128 rows. 32-key tiles via global_load_lds.
__global__ __launch_bounds__(256) void attn_kernel(
    const _Float16* __restrict__ Qh, const _Float16* __restrict__ Kh,
    const _Float16* __restrict__ Vt, _Float16* __restrict__ Y)
{
    __shared__ _Float16 Ks[2][32][32];   // [kchunk][key][32 halves]  4 KB
    __shared__ _Float16 Vs[64][32];      // [d][key]                  4 KB
    __shared__ _Float16 Ps[4][32][32];   // per-wave [row][key]       8 KB

    const int tid  = threadIdx.x;
    const int wave = tid >> 6;
    const int lane = tid & 63;
    const int quad = lane >> 4;
    const int n16  = lane & 15;
    const int h  = blockIdx.y;
    const int qt = gridDim.x - 1 - blockIdx.x;   // longest blocks first
    const int q0 = qt * 128;
    const int rowbase = q0 + wave * 32;

    const _Float16* Qg = Qh + (size_t)h * TT * HD;
    const _Float16* Kg = Kh + (size_t)h * TT * HD;
    const _Float16* Vg = Vt + (size_t)h * TT * HD;   // [d][t]

    // Q fragments: 2 row groups x 2 k-chunks
    half8v aQ[2][2];
#pragma unroll
    for (int g = 0; g < 2; g++) {
        const int row = rowbase + g * 16 + n16;
#pragma unroll
        for (int c = 0; c < 2; c++)
            aQ[g][c] = *(const half8v*)(Qg + (size_t)row * HD + c * 32 + quad * 8);
    }

    f32x4 O[2][4];
#pragma unroll
    for (int g = 0; g < 2; g++)
#pragma unroll
        for (int d = 0; d < 4; d++) O[g][d] = (f32x4){0.f, 0.f, 0.f, 0.f};
    float l[2][4] = {{0.f, 0.f, 0.f, 0.f}, {0.f, 0.f, 0.f, 0.f}};

    // staging addresses (GLDS: lds dst = wave-uniform base + lane*16B)
    const int kc = tid >> 7, kj = (tid >> 2) & 31, ks = tid & 3;
    const _Float16* kSrc = Kg + (size_t)kj * HD + kc * 32 + ks * 8;
    const int vd = tid >> 2, vs = tid & 3;
    const _Float16* vSrc = Vg + (size_t)vd * TT + vs * 8;
    _Float16* ksBase = &Ks[0][0][0] + (size_t)wave * 512;
    _Float16* vsBase = &Vs[0][0] + (size_t)wave * 512;

    const int nTiles = qt * 4 + 4;

    for (int it = 0; it < nTiles; ++it) {
        const int j0 = it * 32;
        __syncthreads();
        GLDS16(kSrc + (size_t)j0 * HD, ksBase);
        GLDS16(vSrc + j0, vsBase);
        __syncthreads();

        if (j0 <= rowbase + 31) {                    // wave not fully masked
            const bool needMask = (j0 + 31 > rowbase);

            // S = Q K^T
            f32x4 S[2][2];
#pragma unroll
            for (int g = 0; g < 2; g++)
#pragma unroll
                for (int st = 0; st < 2; st++) {
                    S[g][st] = (f32x4){0.f, 0.f, 0.f, 0.f};
#pragma unroll
                    for (int c = 0; c < 2; c++) {
                        half8v bK = *(const half8v*)&Ks[c][st * 16 + n16][quad * 8];
                        S[g][st] = __builtin_amdgcn_mfma_f32_16x16x32_f16(
                            aQ[g][c], bK, S[g][st], 0, 0, 0);
                    }
                }

            // exact softmax, no max subtraction (scores pre-scaled by log2e)
#pragma unroll
            for (int g = 0; g < 2; g++)
#pragma unroll
                for (int r = 0; r < 4; r++) {
                    const int row = rowbase + g * 16 + quad * 4 + r;
                    float x0 = S[g][0][r];
                    float x1 = S[g][1][r];
                    if (needMask) {
                        x0 = (j0 + n16      <= row) ? x0 : -1e30f;
                        x1 = (j0 + 16 + n16 <= row) ? x1 : -1e30f;
                    }
                    const float p0 = __builtin_amdgcn_exp2f(x0);
                    const float p1 = __builtin_amdgcn_exp2f(x1);
                    l[g][r] += p0 + p1;
                    Ps[wave][g * 16 + quad * 4 + r][n16]      = (_Float16)p0;
                    Ps[wave][g * 16 + quad * 4 + r][16 + n16] = (_Float16)p1;
                }

            // O += P V
            half8v bV[4];
#pragma unroll
            for (int d = 0; d < 4; d++)
                bV[d] = *(const half8v*)&Vs[d * 16 + n16][quad * 8];
#pragma unroll
            for (int g = 0; g < 2; g++) {
                half8v aP = *(const half8v*)&Ps[wave][g * 16 + n16][quad * 8];
#pragma unroll
                for (int d = 0; d < 4; d++)
                    O[g][d] = __builtin_amdgcn_mfma_f32_16x16x32_f16(
                        aP, bV[d], O[g][d], 0, 0, 0);
            }
        }
    }

    // epilogue: single l reduction + normalize + store
#pragma unroll
    for (int g = 0; g < 2; g++)
#pragma unroll
        for (int r = 0; r < 4; r++) {
            float s = l[g][r];
            s += __shfl_xor(s, 1);
            s += __shfl_xor(s, 2);
            s += __shfl_xor(s, 4);
            s += __shfl_xor(s, 8);
            const float inv = 1.0f / s;
            const int row = rowbase + g * 16 + quad * 4 + r;
            _Float16* yrow = Y + (size_t)row * DD + h * HD;
#pragma unroll
            for (int d = 0; d < 4; d++)
                yrow[d * 16 + n16] = (_Float16)(O[g][d][r] * inv);
        }
}

extern "C" void kernel_launch(void* const* d_in, const int* in_sizes, int n_in,
                              void* d_out, int out_size, void* d_ws, size_t ws_size,
                              hipStream_t stream)
{
    const float* x      = (const float*)d_in[0];
    const float* w_qkv  = (const float*)d_in[1];
    const float* w_proj = (const float*)d_in[2];
    float* out = (float*)d_out;

    char* ws = (char*)d_ws;
    const size_t MB = 1u << 20;
    _Float16* xh  = (_Float16*)(ws);               //  8 MB
    _Float16* WqT = (_Float16*)(ws + 8 * MB);      //  6 MB
    _Float16* WpT = (_Float16*)(ws + 14 * MB);     //  2 MB
    _Float16* Qh  = (_Float16*)(ws + 16 * MB);     //  8 MB
    _Float16* Kh  = (_Float16*)(ws + 24 * MB);     //  8 MB
    _Float16* Vh  = (_Float16*)(ws + 32 * MB);     //  8 MB
    _Float16* Vtg = (_Float16*)(ws + 40 * MB);     //  8 MB
    _Float16* Yh  = (_Float16*)(ws + 48 * MB);     //  8 MB

    dim3 blk(256);

    cast_x<<<(TT * DD) / (256 * 8), blk, 0, stream>>>(x, xh);
    transpose_cast<<<dim3(3072 / 64, DD / 64), blk, 0, stream>>>(w_qkv, WqT, DD, 3 * DD);
    transpose_cast<<<dim3(DD / 64, DD / 64), blk, 0, stream>>>(w_proj, WpT, DD, DD);

    gemm_h<1><<<dim3(3072 / 128, TT / 128), blk, 0, stream>>>(
        xh, WqT, nullptr, Qh, Kh, Vh, TT, 3 * DD, DD);

    rope_h<<<(NH * TT * 32) / 256, blk, 0, stream>>>(Qh, Kh);
    transpose_v<<<dim3(TT / 256, NH), blk, 0, stream>>>(Vh, Vtg);

    attn_kernel<<<dim3(TT / 128, NH), blk, 0, stream>>>(Qh, Kh, Vtg, Yh);

    gemm_h<0><<<dim3(DD / 128, TT / 128), blk, 0, stream>>>(
        Yh, WpT, out, nullptr, nullptr, nullptr, TT, DD, DD);
}

// Round 5
// 281.331 us; speedup vs baseline: 14.3016x; 1.1094x over previous
//
#include <hip/hip_runtime.h>
#include <hip/hip_fp16.h>
#include <math.h>

#define TT 4096
#define DD 1024
#define NH 16
#define HD 64

typedef __attribute__((ext_vector_type(8))) _Float16 half8v;
typedef __attribute__((ext_vector_type(4))) _Float16 half4v;
typedef __attribute__((ext_vector_type(4))) float f32x4;

#define GLDS16(g, l)                                                        \
    __builtin_amdgcn_global_load_lds(                                       \
        (const __attribute__((address_space(1))) void*)(g),                 \
        (__attribute__((address_space(3))) void*)(l), 16, 0, 0)

// ---------------- cast x -> fp16 ----------------
__global__ __launch_bounds__(256) void cast_x(const float* __restrict__ X,
                                              _Float16* __restrict__ Xh)
{
    const int i = (blockIdx.x * 256 + threadIdx.x) * 8;
    float4 a = *(const float4*)&X[i];
    float4 b = *(const float4*)&X[i + 4];
    half8v o = {(_Float16)a.x, (_Float16)a.y, (_Float16)a.z, (_Float16)a.w,
                (_Float16)b.x, (_Float16)b.y, (_Float16)b.z, (_Float16)b.w};
    *(half8v*)&Xh[i] = o;
}

// ---------------- transpose+cast W[K][N] fp32 -> WT[N][K] fp16 ----------------
__global__ __launch_bounds__(256) void transpose_cast(
    const float* __restrict__ W, _Float16* __restrict__ WT, int K, int N)
{
    __shared__ float tile[64][65];
    const int t = threadIdx.x;
    const int k0 = blockIdx.y * 64, n0 = blockIdx.x * 64;
    const int c = (t & 15) * 4, r = t >> 4;
#pragma unroll
    for (int i = 0; i < 4; i++) {
        float4 v = *(const float4*)&W[(size_t)(k0 + r + 16 * i) * N + n0 + c];
        tile[r + 16 * i][c + 0] = v.x;
        tile[r + 16 * i][c + 1] = v.y;
        tile[r + 16 * i][c + 2] = v.z;
        tile[r + 16 * i][c + 3] = v.w;
    }
    __syncthreads();
#pragma unroll
    for (int i = 0; i < 4; i++) {
        const int n = r + 16 * i;
        half4v o;
        o[0] = (_Float16)tile[c + 0][n];
        o[1] = (_Float16)tile[c + 1][n];
        o[2] = (_Float16)tile[c + 2][n];
        o[3] = (_Float16)tile[c + 3][n];
        *(half4v*)&WT[(size_t)(n0 + n) * K + k0 + c] = o;
    }
}

// ---------------- fp16 MFMA GEMM: C[M,N] = A[M,K] * Bt[N,K]^T ----------------
template <int MODE>
__global__ __launch_bounds__(256) void gemm_h(
    const _Float16* __restrict__ A, const _Float16* __restrict__ Bt,
    float* __restrict__ C0, _Float16* __restrict__ Q,
    _Float16* __restrict__ Kk, _Float16* __restrict__ V,
    int M, int N, int K)
{
    __shared__ _Float16 As[128 * 32];
    __shared__ _Float16 Bs[128 * 32];
    const int tid  = threadIdx.x;
    const int wave = tid >> 6;
    const int lane = tid & 63;
    const int quad = lane >> 4;
    const int n16  = lane & 15;
    const int n0 = blockIdx.x * 128;
    const int m0 = blockIdx.y * 128;
    const int wr = (wave & 1) * 64;
    const int wc = (wave >> 1) * 64;

    f32x4 acc[4][4];
#pragma unroll
    for (int i = 0; i < 4; i++)
#pragma unroll
        for (int j = 0; j < 4; j++) acc[i][j] = (f32x4){0.f, 0.f, 0.f, 0.f};

    const int srow = tid >> 2;
    const int scol = (tid & 3) * 8;
    const _Float16* Ag = A + (size_t)(m0 + srow) * K + scol;
    const _Float16* Bg = Bt + (size_t)(n0 + srow) * K + scol;
    _Float16* AsW = As + (size_t)wave * 512;
    _Float16* BsW = Bs + (size_t)wave * 512;

    for (int k0 = 0; k0 < K; k0 += 32) {
        __syncthreads();
        GLDS16(Ag + k0, AsW);
        GLDS16(Ag + (size_t)64 * K + k0, AsW + 2048);
        GLDS16(Bg + k0, BsW);
        GLDS16(Bg + (size_t)64 * K + k0, BsW + 2048);
        __syncthreads();

        half8v aF[4], bF[4];
#pragma unroll
        for (int i = 0; i < 4; i++)
            aF[i] = *(const half8v*)&As[(size_t)(wr + i * 16 + n16) * 32 + quad * 8];
#pragma unroll
        for (int j = 0; j < 4; j++)
            bF[j] = *(const half8v*)&Bs[(size_t)(wc + j * 16 + n16) * 32 + quad * 8];
#pragma unroll
        for (int i = 0; i < 4; i++)
#pragma unroll
            for (int j = 0; j < 4; j++)
                acc[i][j] = __builtin_amdgcn_mfma_f32_16x16x32_f16(
                    aF[i], bF[j], acc[i][j], 0, 0, 0);
    }

#pragma unroll
    for (int i = 0; i < 4; i++) {
#pragma unroll
        for (int j = 0; j < 4; j++) {
#pragma unroll
            for (int r = 0; r < 4; r++) {
                const int m = m0 + wr + i * 16 + quad * 4 + r;
                const int n = n0 + wc + j * 16 + n16;
                const float val = acc[i][j][r];
                if (MODE == 0) {
                    C0[(size_t)m * N + n] = val;
                } else {
                    const int which = n >> 10;
                    const int col = n & 1023;
                    const int h = col >> 6, d = col & 63;
                    const size_t off = ((size_t)h * TT + m) * HD + d;
                    if (which == 0) Q[off] = (_Float16)val;
                    else if (which == 1) Kk[off] = (_Float16)val;
                    else V[off] = (_Float16)val;
                }
            }
        }
    }
}

// ---------------- RoPE in-place; Q scaled by 0.125*log2(e) ----------------
__global__ __launch_bounds__(256) void rope_h(_Float16* __restrict__ Q,
                                              _Float16* __restrict__ Kb)
{
    const int idx = blockIdx.x * 256 + threadIdx.x;
    const int i = idx & 31;
    const int t = (idx >> 5) & (TT - 1);
    const int h = idx >> 17;
    if (h >= NH) return;

    const float inv = expf(-(float)i * (logf(10000.0f) / 32.0f));
    const float f = (float)t * inv;
    const float c = cosf(f), s = sinf(f);
    const size_t base = ((size_t)h * TT + t) * HD + i;
    const float QS = 0.125f * 1.44269504f;

    float q1 = (float)Q[base], q2 = (float)Q[base + 32];
    Q[base]      = (_Float16)((q1 * c - q2 * s) * QS);
    Q[base + 32] = (_Float16)((q2 * c + q1 * s) * QS);
    float k1 = (float)Kb[base], k2 = (float)Kb[base + 32];
    Kb[base]      = (_Float16)(k1 * c - k2 * s);
    Kb[base + 32] = (_Float16)(k2 * c + k1 * s);
}

// ---------------- V: [h][t][d] -> Vp[h][kb][d][32] with key-permuted cols ----
// key(c') = (c'>>1) + 16*(c'&1) within each 32-key block.
__global__ __launch_bounds__(256) void transpose_v(
    const _Float16* __restrict__ V, _Float16* __restrict__ Vp)
{
    __shared__ _Float16 tile[256][72];
    const int h = blockIdx.y;
    const int t0 = blockIdx.x * 256;
    const int tid = threadIdx.x;
    const _Float16* Vg = V + (size_t)h * TT * HD;

#pragma unroll
    for (int i = 0; i < 4; i++) {
        const int chunk = tid + 256 * i;
        const int row = chunk >> 2, c = (chunk & 3) * 16;
        half8v v0 = *(const half8v*)(Vg + (size_t)(t0 + row) * HD + c);
        half8v v1 = *(const half8v*)(Vg + (size_t)(t0 + row) * HD + c + 8);
        *(half8v*)&tile[row][c] = v0;
        *(half8v*)&tile[row][c + 8] = v1;
    }
    __syncthreads();

    _Float16* Vo = Vp + ((size_t)h * (TT / 32) + (t0 >> 5)) * 64 * 32;
#pragma unroll
    for (int i = 0; i < 8; i++) {
        const int item = tid + 256 * i;          // (kbl, d, c-chunk)
        const int cc = (item & 3) * 8;
        const int d = (item >> 2) & 63;
        const int kbl = item >> 8;
        half8v o;
#pragma unroll
        for (int e = 0; e < 8; e++) {
            const int cp = cc + e;
            const int key = (cp >> 1) + 16 * (cp & 1);
            o[e] = tile[kbl * 32 + key][d];
        }
        *(half8v*)(Vo + ((size_t)kbl * 64 + d) * 32 + cc) = o;
    }
}

// ---------------- zero O/L accumulators ----------------
__global__ __launch_bounds__(256) void zero_acc(float4* __restrict__ O4,
                                                float4* __restrict__ L4)
{
    const int i = blockIdx.x * 256 + threadIdx.x;   // 524288
    const float4 z = {0.f, 0.f, 0.f, 0.f};
    O4[i] = z;
    if (i < 16384) L4[i] = z;
}

// ---------------- split-K MFMA flash attention (no-max exact softmax) -------
// grid (slice=4, qt=32, h=16); block = 4 waves x 32 q-rows = 128 rows.
// Unnormalized partials accumulated via pk_f16 atomics into Oacc, f32 Lacc.
__global__ __launch_bounds__(256) void attn_kernel(
    const _Float16* __restrict__ Qh, const _Float16* __restrict__ Kh,
    const _Float16* __restrict__ Vp, _Float16* __restrict__ Oacc,
    float* __restrict__ Lacc)
{
    __shared__ _Float16 Ks[2][32][32];   // [kchunk][key][32]      4 KB
    __shared__ _Float16 Vs[64][32];      // [d][key-perm]          4 KB
    __shared__ _Float16 Ps[4][32][40];   // per-wave [row][c'] pad 10 KB

    const int tid  = threadIdx.x;
    const int wave = tid >> 6;
    const int lane = tid & 63;
    const int quad = lane >> 4;
    const int n16  = lane & 15;
    const int h  = blockIdx.z;
    const int qt = 31 - blockIdx.y;          // longest first
    const int s  = blockIdx.x;
    const int nT = 4 * qt + 4;
    const int nS = (qt + 8) >> 3;            // ceil((qt+1)/8)
    if (s >= nS) return;
    const int t_beg = s * nT / nS;
    const int t_end = (s + 1) * nT / nS;

    const int q0 = qt * 128;
    const int rowbase = q0 + wave * 32;

    const _Float16* Qg = Qh + (size_t)h * TT * HD;
    const _Float16* Kg = Kh + (size_t)h * TT * HD;
    const _Float16* Vg = Vp + (size_t)h * (TT / 32) * 64 * 32;

    half8v aQ[2][2];
#pragma unroll
    for (int g = 0; g < 2; g++) {
        const int row = rowbase + g * 16 + n16;
#pragma unroll
        for (int c = 0; c < 2; c++)
            aQ[g][c] = *(const half8v*)(Qg + (size_t)row * HD + c * 32 + quad * 8);
    }

    f32x4 O[2][4];
#pragma unroll
    for (int g = 0; g < 2; g++)
#pragma unroll
        for (int d = 0; d < 4; d++) O[g][d] = (f32x4){0.f, 0.f, 0.f, 0.f};
    float l[2][4] = {{0.f, 0.f, 0.f, 0.f}, {0.f, 0.f, 0.f, 0.f}};

    const int kc = tid >> 7, kj = (tid >> 2) & 31, ks = tid & 3;
    const _Float16* kSrc = Kg + (size_t)kj * HD + kc * 32 + ks * 8;
    const _Float16* vSrc = Vg + (size_t)tid * 8;
    _Float16* ksBase = &Ks[0][0][0] + (size_t)wave * 512;
    _Float16* vsBase = &Vs[0][0] + (size_t)wave * 512;

    for (int it = t_beg; it < t_end; ++it) {
        const int j0 = it * 32;
        __syncthreads();
        GLDS16(kSrc + (size_t)j0 * HD, ksBase);
        GLDS16(vSrc + (size_t)it * 2048, vsBase);
        __syncthreads();

        if (j0 <= rowbase + 31) {
            const bool needMask = (j0 + 31 > rowbase);

            f32x4 S[2][2];
#pragma unroll
            for (int g = 0; g < 2; g++)
#pragma unroll
                for (int st = 0; st < 2; st++) {
                    S[g][st] = (f32x4){0.f, 0.f, 0.f, 0.f};
#pragma unroll
                    for (int c = 0; c < 2; c++) {
                        half8v bK = *(const half8v*)&Ks[c][st * 16 + n16][quad * 8];
                        S[g][st] = __builtin_amdgcn_mfma_f32_16x16x32_f16(
                            aQ[g][c], bK, S[g][st], 0, 0, 0);
                    }
                }

#pragma unroll
            for (int g = 0; g < 2; g++)
#pragma unroll
                for (int r = 0; r < 4; r++) {
                    const int row = rowbase + g * 16 + quad * 4 + r;
                    float x0 = S[g][0][r];
                    float x1 = S[g][1][r];
                    if (needMask) {
                        x0 = (j0 + n16      <= row) ? x0 : -1e30f;
                        x1 = (j0 + 16 + n16 <= row) ? x1 : -1e30f;
                    }
                    const float p0 = __builtin_amdgcn_exp2f(x0);
                    const float p1 = __builtin_amdgcn_exp2f(x1);
                    l[g][r] += p0 + p1;
                    // packed store: c' = 2*n16 (key n16), 2*n16+1 (key 16+n16)
                    *(__half2*)&Ps[wave][g * 16 + quad * 4 + r][2 * n16] =
                        __floats2half2_rn(p0, p1);
                }

            half8v bV[4];
#pragma unroll
            for (int d = 0; d < 4; d++)
                bV[d] = *(const half8v*)&Vs[d * 16 + n16][quad * 8];
#pragma unroll
            for (int g = 0; g < 2; g++) {
                half8v aP = *(const half8v*)&Ps[wave][g * 16 + n16][quad * 8];
#pragma unroll
                for (int d = 0; d < 4; d++)
                    O[g][d] = __builtin_amdgcn_mfma_f32_16x16x32_f16(
                        aP, bV[d], O[g][d], 0, 0, 0);
            }
        }
    }

    // epilogue: atomic partial accumulate
#pragma unroll
    for (int g = 0; g < 2; g++)
#pragma unroll
        for (int r = 0; r < 4; r++) {
            float sl = l[g][r];
            sl += __shfl_xor(sl, 1);
            sl += __shfl_xor(sl, 2);
            sl += __shfl_xor(sl, 4);
            sl += __shfl_xor(sl, 8);
            const int row = rowbase + g * 16 + quad * 4 + r;
            if (n16 == 0)
                unsafeAtomicAdd(&Lacc[h * TT + row], sl);
#pragma unroll
            for (int d = 0; d < 4; d++) {
                float v = O[g][d][r];
                float vn = __shfl_xor(v, 1);
                if ((lane & 1) == 0) {
                    __half2* dst = (__half2*)(Oacc +
                        ((size_t)h * TT + row) * HD + d * 16 + n16);
                    unsafeAtomicAdd(dst, __floats2half2_rn(v, vn));
                }
            }
        }
}

// ---------------- finalize: Y[t][h*64+d] = Oacc/Lacc (fp16) ----------------
__global__ __launch_bounds__(256) void finalize(
    const _Float16* __restrict__ Oacc, const float* __restrict__ Lacc,
    _Float16* __restrict__ Y)
{
    const int gid = blockIdx.x * 256 + threadIdx.x;   // 524288
    const int h = gid >> 15;
    const int rem = gid & 32767;
    const int t = rem >> 3;
    const int c = rem & 7;
    const float inv = 1.0f / Lacc[h * TT + t];
    half8v o = *(const half8v*)(Oacc + ((size_t)h * TT + t) * HD + c * 8);
    half8v y;
#pragma unroll
    for (int e = 0; e < 8; e++) y[e] = (_Float16)((float)o[e] * inv);
    *(half8v*)(Y + (size_t)t * DD + h * HD + c * 8) = y;
}

extern "C" void kernel_launch(void* const* d_in, const int* in_sizes, int n_in,
                              void* d_out, int out_size, void* d_ws, size_t ws_size,
                              hipStream_t stream)
{
    const float* x      = (const float*)d_in[0];
    const float* w_qkv  = (const float*)d_in[1];
    const float* w_proj = (const float*)d_in[2];
    float* out = (float*)d_out;

    char* ws = (char*)d_ws;
    const size_t MB = 1u << 20;
    _Float16* xh   = (_Float16*)(ws);               //  8 MB
    _Float16* WqT  = (_Float16*)(ws + 8 * MB);      //  6 MB
    _Float16* WpT  = (_Float16*)(ws + 14 * MB);     //  2 MB
    _Float16* Qh   = (_Float16*)(ws + 16 * MB);     //  8 MB
    _Float16* Kh   = (_Float16*)(ws + 24 * MB);     //  8 MB
    _Float16* Vh   = (_Float16*)(ws + 32 * MB);     //  8 MB
    _Float16* Vp   = (_Float16*)(ws + 40 * MB);     //  8 MB
    _Float16* Yh   = (_Float16*)(ws + 48 * MB);     //  8 MB
    _Float16* Oacc = (_Float16*)(ws + 56 * MB);     //  8.4 MB
    float*    Lacc = (float*)(ws + 65 * MB);        //  0.26 MB

    dim3 blk(256);

    cast_x<<<(TT * DD) / (256 * 8), blk, 0, stream>>>(x, xh);
    transpose_cast<<<dim3(3072 / 64, DD / 64), blk, 0, stream>>>(w_qkv, WqT, DD, 3 * DD);
    transpose_cast<<<dim3(DD / 64, DD / 64), blk, 0, stream>>>(w_proj, WpT, DD, DD);

    gemm_h<1><<<dim3(3072 / 128, TT / 128), blk, 0, stream>>>(
        xh, WqT, nullptr, Qh, Kh, Vh, TT, 3 * DD, DD);

    rope_h<<<(NH * TT * 32) / 256, blk, 0, stream>>>(Qh, Kh);
    transpose_v<<<dim3(TT / 256, NH), blk, 0, stream>>>(Vh, Vp);
    zero_acc<<<2048, blk, 0, stream>>>((float4*)Oacc, (float4*)Lacc);

    attn_kernel<<<dim3(4, 32, NH), blk, 0, stream>>>(Qh, Kh, Vp, Oacc, Lacc);

    finalize<<<2048, blk, 0, stream>>>(Oacc, Lacc, Yh);

    gemm_h<0><<<dim3(DD / 128, TT / 128), blk, 0, stream>>>(
        Yh, WpT, out, nullptr, nullptr, nullptr, TT, DD, DD);
}